// Round 13
// baseline (274.363 us; speedup 1.0000x reference)
//
#include <hip/hip_runtime.h>
#include <math.h>
#include <utility>

// N = 100000 nodes, SEQ = 16, layers: 3 ->16 ->32 ->64 ->128 ->256 ->12(log_softmax)
// bf16 MFMA, barrier-free K-loop (R12 baseline) + SHARED-A variant for spiral3:
//   SHA mode (CW=2): the two column-waves of a pair share ONE per-pair A double buffer
//   (16 KB total LDS). Only wc==0 gathers (halves DMA+idx insts). Producer does exact
//   s_waitcnt vmcnt(N) then raw s_barrier (publish, no drain); after ds_read+lgkmcnt(0)
//   a second raw s_barrier closes the WAR window before DMA(s+1) overwrites the buffer
//   read two steps ago. Epilogue two-pass to fit 16 KB.
//   Non-SHA layers identical to R12 (per-wave buffers, no in-loop barriers).

typedef __bf16 bf16x8 __attribute__((ext_vector_type(8)));
typedef float f32x16 __attribute__((ext_vector_type(16)));

template <int V> using ic = std::integral_constant<int, V>;

template <typename F, int... Is>
__device__ __forceinline__ void static_for_impl(F&& f, std::integer_sequence<int, Is...>) {
    (f(ic<Is>{}), ...);
}
template <int N_, typename F>
__device__ __forceinline__ void static_for(F&& f) {
    static_for_impl(static_cast<F&&>(f), std::make_integer_sequence<int, N_>{});
}

template <int N_>
__device__ __forceinline__ void wait_vmcnt() {
    static_assert(N_ <= 63, "vmcnt range");
    // gfx9 encoding: vmcnt[3:0] | expcnt<<4 | lgkmcnt<<8 | vmcnt[5:4]<<14 (exp/lgkm = no-wait)
    __builtin_amdgcn_s_waitcnt((N_ & 0xF) | (0x7 << 4) | (0xF << 8) | ((N_ >> 4) << 14));
}
__device__ __forceinline__ void wait_lgkmcnt0() {
    // vmcnt=63 (no wait), expcnt=7 (no wait), lgkmcnt=0
    __builtin_amdgcn_s_waitcnt(0xF | (0x7 << 4) | (0 << 8) | (0x3 << 14));
}

// fence: pin VMEM/DS order, allow ALU/SALU/MFMA to cross
__device__ __forceinline__ void memfence_sched() { __builtin_amdgcn_sched_barrier(0x000F); }

__device__ __forceinline__ float elu_f(float v) { return v > 0.f ? v : expm1f(v); }

// ------------------------------------------------ weight prep: fp32 -> bf16, frag-major swizzle
// dst chunk ((k/64)*8 + (k%64)/8)*COUT + col, element k%8  <-  src[col*K + k]
template <int K, int C>
__device__ __forceinline__ void swz_one(const float* __restrict__ src, __bf16* __restrict__ dst, int j)
{
    int col = j / K;          // K is pow2
    int k = j & (K - 1);
    int chunk = ((k >> 6) * 8 + ((k & 63) >> 3)) * C + col;
    dst[chunk * 8 + (k & 7)] = (__bf16)src[j];
}

__global__ __launch_bounds__(256) void cvt_swz_kernel(const float* __restrict__ w1,
                                                      const float* __restrict__ w2,
                                                      const float* __restrict__ w3,
                                                      const float* __restrict__ f1,
                                                      const float* __restrict__ f2,
                                                      __bf16* __restrict__ d1,
                                                      __bf16* __restrict__ d2,
                                                      __bf16* __restrict__ d3,
                                                      __bf16* __restrict__ df1,
                                                      __bf16* __restrict__ df2)
{
    int i = blockIdx.x * 256 + threadIdx.x;
    if (i < 8192)        swz_one<256, 32>(w1, d1, i);
    else if (i < 40960)  swz_one<512, 64>(w2, d2, i - 8192);
    else if (i < 172032) swz_one<1024, 128>(w3, d3, i - 40960);
    else if (i < 204800) swz_one<128, 256>(f1, df1, i - 172032);
    else if (i < 207872) df2[i - 204800] = (__bf16)f2[i - 204800];   // fc2 stays row-major
}

// ------------------------------------------------ idx transpose: idxT[s*N + n] = idx[n*16 + s]
__global__ __launch_bounds__(256) void idxT_kernel(const int* __restrict__ idx,
                                                   int* __restrict__ idxT, int N)
{
    int i = blockIdx.x * 256 + threadIdx.x;
    if (i >= N * 16) return;
    int n = i >> 4, s = i & 15;
    idxT[s * N + n] = idx[i];
}

// ---------------------------------------------------------------- fc0: [N,3] -> [N,16] bf16
__global__ __launch_bounds__(256) void fc0_kernel(const float* __restrict__ x,
                                                  const float* __restrict__ w,
                                                  const float* __restrict__ b,
                                                  __bf16* __restrict__ h0, int N)
{
    int n = blockIdx.x * 256 + threadIdx.x;
    if (n >= N) return;
    float x0 = x[n * 3 + 0], x1 = x[n * 3 + 1], x2 = x[n * 3 + 2];
    __bf16 ob[16];
#pragma unroll
    for (int j = 0; j < 16; ++j)
        ob[j] = (__bf16)elu_f(w[j * 3 + 0] * x0 + w[j * 3 + 1] * x1 + w[j * 3 + 2] * x2 + b[j]);
    int4* dst = (int4*)&h0[(size_t)n * 16];
    dst[0] = *(int4*)&ob[0];
    dst[1] = *(int4*)&ob[8];
}

// ------------------------------------------- depth-1 pipelined MFMA gather-GEMM
template <int CIN, int S, int COUT_B, int COUT_TOT, int TILE_M, int RW, int CW,
          bool GATHER, bool SHA, int MINW, int NN>
__global__ __launch_bounds__(256, MINW) void mfma_layer(const __bf16* __restrict__ hin,
                                                        const int* __restrict__ idxT,
                                                        const __bf16* __restrict__ Wsw,
                                                        const float* __restrict__ bias,
                                                        __bf16* __restrict__ hout)
{
    constexpr int K = CIN * S;
    constexpr int NSTEP = K / 64;
    static_assert(K % 64 == 0, "K%64");
    constexpr int WM = TILE_M / RW;        // rows per wave
    constexpr int WN = COUT_B / CW;
    constexpr int MT = WM / 32;            // row subtiles per wave
    constexpr int NT = WN / 32;
    constexpr int IPS = GATHER ? (64 / CIN) : 1;
    constexpr int D = WM / 8;              // DMA insts per step (per producer wave)
    constexpr int Bn = NT * 4;             // B vmem loads per step
    constexpr int I = GATHER ? D : 0;      // idx vmem loads per step
    constexpr int NBUFS = 2;
    constexpr int NSTAGE = SHA ? RW : 4;   // A buffers: per-pair (SHA) or per-wave
    static_assert(RW * CW == 4, "4 waves");
    static_assert(WM == 32 || WM == 64, "1-2 row subtiles per wave");
    static_assert(!SHA || (CW == 2 && WM == 32), "SHA needs CW=2, WM=32");

    constexpr int AB = NSTAGE * NBUFS * WM * 128;         // A staging bytes
    constexpr int CB = (SHA ? 32 : TILE_M) * (COUT_B + 8) * 2;  // epilogue staging
    constexpr int SH = AB > CB ? AB : CB;
    __shared__ __align__(16) char smem[SH];

    const int tid = threadIdx.x;
    const int lane = tid & 63;
    const int w = tid >> 6;
    const int wr = w / CW;
    const int wc = w % CW;
    const int ml = lane & 31;
    const int kh = lane >> 5;
    const int m0 = blockIdx.x * TILE_M;
    const int col0 = blockIdx.y * COUT_B;
    const int rbase = m0 + wr * WM;

    char* const Aw = smem + (SHA ? wr : w) * (NBUFS * WM * 128);
    const bool prod = !SHA || (wc == 0);   // wave-uniform

    // ---- per-lane DMA geometry (computed once)
    int ioff[GATHER ? D : 1];      // gather: j*NN + clamped row
    int koff[GATHER ? D : 1];      // gather: channel offset within node row
    int gmr[GATHER ? 1 : D];       // dense: clamped rows
    int coff[GATHER ? 1 : D];      // dense: chunk element offset
#pragma unroll
    for (int i = 0; i < D; ++i) {
        int r = i * 8 + (lane >> 3);
        int c = (lane & 7) ^ (r & 7);
        int gm = rbase + r; if (gm >= NN) gm = NN - 1;
        if constexpr (GATHER) {
            ioff[i] = ((c * 8) / CIN) * NN + gm;
            koff[i] = (c * 8) & (CIN - 1);
        } else {
            gmr[i] = gm;
            coff[i] = c * 8;
        }
    }

    bf16x8 bfr[2][NT][4];
    int myIdx[GATHER ? 3 : 1][GATHER ? D : 1];

    const __bf16* wlane = Wsw + ((size_t)(col0 + wc * WN + ml) + (size_t)kh * COUT_TOT) * 8;

    auto loadB = [&](auto sc) {
        constexpr int s = decltype(sc)::value;
        if constexpr (s < NSTEP) {
#pragma unroll
            for (int ni = 0; ni < NT; ++ni)
#pragma unroll
                for (int ks = 0; ks < 4; ++ks)
                    bfr[s & 1][ni][ks] = *(const bf16x8*)(wlane
                        + (size_t)(s * 8 + ks * 2) * COUT_TOT * 8 + ni * 32 * 8);
        }
    };
    auto loadIdxS = [&](auto sc) {
        constexpr int s = decltype(sc)::value;
        if constexpr (GATHER && s < NSTEP) {
            if (prod) {
#pragma unroll
                for (int i = 0; i < D; ++i)
                    myIdx[s % 3][i] = idxT[(s * IPS) * NN + ioff[i]];
            }
        }
    };
    auto issueDMA = [&](auto sc) {
        constexpr int s = decltype(sc)::value;
        if constexpr (s < NSTEP) {
            if (prod) {
                char* base = Aw + (s % NBUFS) * (WM * 128);
#pragma unroll
                for (int i = 0; i < D; ++i) {
                    const __bf16* src;
                    if constexpr (GATHER)
                        src = hin + (size_t)myIdx[s % 3][i] * CIN + koff[i];
                    else
                        src = hin + (size_t)gmr[i] * K + s * 64 + coff[i];
                    __builtin_amdgcn_global_load_lds(
                        (const __attribute__((address_space(1))) void*)src,
                        (__attribute__((address_space(3))) void*)(base + i * 1024),
                        16, 0, 0);
                }
            }
        }
    };

    f32x16 acc[MT][NT];
#pragma unroll
    for (int mi = 0; mi < MT; ++mi)
#pragma unroll
        for (int ni = 0; ni < NT; ++ni) { f32x16 z = {}; acc[mi][ni] = z; }

    // ---- prologue (mirrors in-loop group order so producer vmcnt counts stay exact)
    loadIdxS(ic<0>{});
    loadIdxS(ic<1>{});
    memfence_sched();
    loadB(ic<0>{});
    memfence_sched();
    issueDMA(ic<0>{});
    memfence_sched();
    loadIdxS(ic<2>{});
    memfence_sched();

    // ---- K-loop: [B(s+1)] [DMA(s+1)] [idx(s+3)] | prod: wait DMA(s) | (SHA: barrier)
    //      ds_read A(s) | (SHA: lgkm0 + barrier) | MFMA
    static_for<NSTEP>([&](auto sc) {
        constexpr int s = decltype(sc)::value;
        loadB(ic<s + 1>{});
        memfence_sched();
        issueDMA(ic<s + 1>{});
        memfence_sched();
        loadIdxS(ic<s + 3>{});
        memfence_sched();
        // producer's vmem ops younger than DMA(s)'s last inst:
        //   idx(s+2) [prev step], B(s+1), DMA(s+1), idx(s+3) [this step]
        constexpr int NW = I * (s + 2 < NSTEP) + (Bn + D) * (s + 1 < NSTEP)
                         + I * (s + 3 < NSTEP);
        if (prod) wait_vmcnt<NW>();            // A(s) resident in LDS
        if constexpr (SHA) __builtin_amdgcn_s_barrier();   // publish A(s) to partner
        memfence_sched();

        const char* base = Aw + (s % NBUFS) * (WM * 128);
        bf16x8 afr[MT][4];
#pragma unroll
        for (int mi = 0; mi < MT; ++mi)
#pragma unroll
            for (int ks = 0; ks < 4; ++ks) {
                int cb = ks * 2 + kh;
                afr[mi][ks] = *(const bf16x8*)(base + ((mi * 32 + ml) * 8 + (cb ^ (ml & 7))) * 16);
            }
        if constexpr (SHA) {
            wait_lgkmcnt0();                   // A(s) reads retired from LDS
            __builtin_amdgcn_s_barrier();      // close WAR window for DMA(s+2) overwrite
        }
#pragma unroll
        for (int ks = 0; ks < 4; ++ks)
#pragma unroll
            for (int mi = 0; mi < MT; ++mi)
#pragma unroll
                for (int ni = 0; ni < NT; ++ni)
                    acc[mi][ni] = __builtin_amdgcn_mfma_f32_32x32x16_bf16(
                        afr[mi][ks], bfr[s & 1][ni][ks], acc[mi][ni], 0, 0, 0);
    });

    // ---- epilogue: acc -> LDS -> coalesced int4 stores
    __syncthreads();
    __bf16* Cs = (__bf16*)smem;
    constexpr int LDC = COUT_B + 8;
    constexpr int C8 = COUT_B / 8;
    if constexpr (SHA) {
        // two passes of 32 rows (by wr) to fit the 16 KB buffer
#pragma unroll
        for (int half = 0; half < 2; ++half) {
            if (wr == half) {
#pragma unroll
                for (int ni = 0; ni < NT; ++ni) {
                    const int col = wc * WN + ni * 32 + ml;
                    const float bv = bias[col0 + col];
#pragma unroll
                    for (int r = 0; r < 16; ++r) {
                        int rowl = (r & 3) + 8 * (r >> 2) + 4 * kh;
                        Cs[rowl * LDC + col] = (__bf16)elu_f(acc[0][ni][r] + bv);
                    }
                }
            }
            __syncthreads();
#pragma unroll
            for (int j2 = tid; j2 < 32 * C8; j2 += 256) {
                int row = j2 / C8, c8 = j2 % C8;
                int gm = m0 + half * 32 + row;
                if (gm < NN)
                    *(int4*)&hout[(size_t)gm * COUT_TOT + col0 + c8 * 8] = *(int4*)&Cs[row * LDC + c8 * 8];
            }
            __syncthreads();
        }
    } else {
#pragma unroll
        for (int ni = 0; ni < NT; ++ni) {
            const int col = wc * WN + ni * 32 + ml;
            const float bv = bias[col0 + col];
#pragma unroll
            for (int mi = 0; mi < MT; ++mi) {
#pragma unroll
                for (int r = 0; r < 16; ++r) {
                    int row = wr * WM + mi * 32 + ((r & 3) + 8 * (r >> 2) + 4 * kh);
                    Cs[row * LDC + col] = (__bf16)elu_f(acc[mi][ni][r] + bv);
                }
            }
        }
        __syncthreads();
#pragma unroll
        for (int j2 = tid; j2 < TILE_M * C8; j2 += 256) {
            int row = j2 / C8, c8 = j2 % C8;
            int gm = m0 + row;
            if (gm < NN)
                *(int4*)&hout[(size_t)gm * COUT_TOT + col0 + c8 * 8] = *(int4*)&Cs[row * LDC + c8 * 8];
        }
    }
}

// ---------------------------------------------------------------- fc2 + log_softmax: [N,256] bf16 -> [N,12] f32
__global__ __launch_bounds__(256) void fc2_kernel(const __bf16* __restrict__ h4,
                                                  const __bf16* __restrict__ Wb,  // [12,256] bf16
                                                  const float* __restrict__ bias,
                                                  float* __restrict__ out, int N)
{
    const int lane = threadIdx.x & 63;
    const int w = threadIdx.x >> 6;
    const int c = lane & 31;
    const int half = lane >> 5;

    bf16x8 wreg[12];
#pragma unroll
    for (int o = 0; o < 12; ++o)
        wreg[o] = *(const bf16x8*)&Wb[o * 256 + c * 8];

    const int base = blockIdx.x * 32 + w * 8;
#pragma unroll
    for (int p = 0; p < 4; ++p) {
        int n = base + p * 2 + half;
        bool valid = n < N;
        int nn = valid ? n : N - 1;
        bf16x8 h = *(const bf16x8*)&h4[(size_t)nn * 256 + c * 8];
        float hf[8];
#pragma unroll
        for (int j = 0; j < 8; ++j) hf[j] = (float)h[j];
        float pr[12];
#pragma unroll
        for (int o = 0; o < 12; ++o) {
            float s = 0.f;
#pragma unroll
            for (int j = 0; j < 8; ++j) s += hf[j] * (float)wreg[o][j];
            pr[o] = s;
        }
#pragma unroll
        for (int off = 16; off > 0; off >>= 1) {
#pragma unroll
            for (int o = 0; o < 12; ++o) pr[o] += __shfl_down(pr[o], off, 32);
        }
        if (c == 0 && valid) {
            float logits[12], mx = -1e30f;
#pragma unroll
            for (int o = 0; o < 12; ++o) {
                logits[o] = pr[o] + bias[o];
                mx = fmaxf(mx, logits[o]);
            }
            float s = 0.f;
#pragma unroll
            for (int o = 0; o < 12; ++o) s += expf(logits[o] - mx);
            float lse = mx + logf(s);
#pragma unroll
            for (int o = 0; o < 12; ++o) out[(size_t)n * 12 + o] = logits[o] - lse;
        }
    }
}

extern "C" void kernel_launch(void* const* d_in, const int* in_sizes, int n_in,
                              void* d_out, int out_size, void* d_ws, size_t ws_size,
                              hipStream_t stream)
{
    const int N = 100000;
    const float* x     = (const float*)d_in[0];
    const int*   idx   = (const int*)  d_in[1];
    const float* fc0_w = (const float*)d_in[2];
    const float* fc0_b = (const float*)d_in[3];
    const float* w1    = (const float*)d_in[4];
    const float* b1    = (const float*)d_in[5];
    const float* w2    = (const float*)d_in[6];
    const float* b2    = (const float*)d_in[7];
    const float* w3    = (const float*)d_in[8];
    const float* b3    = (const float*)d_in[9];
    const float* fc1_w = (const float*)d_in[10];
    const float* fc1_b = (const float*)d_in[11];
    const float* fc2_w = (const float*)d_in[12];
    const float* fc2_b = (const float*)d_in[13];
    float* out = (float*)d_out;

    // ---- workspace layout
    char* ws = (char*)d_ws;
    const int n_w1 = 32 * 256, n_w2 = 64 * 512, n_w3 = 128 * 1024, n_fc1 = 256 * 128, n_fc2 = 12 * 256;
    const int n_wb = n_w1 + n_w2 + n_w3 + n_fc1 + n_fc2;   // 207872
    __bf16* w1b = (__bf16*)ws;
    __bf16* w2b = w1b + n_w1;
    __bf16* w3b = w2b + n_w2;
    __bf16* f1b = w3b + n_w3;
    __bf16* f2b = f1b + n_fc1;
    size_t off = ((size_t)n_wb * 2 + 4095) & ~(size_t)4095;
    int* idxT = (int*)(ws + off);      off += (size_t)N * 16 * 4;
    __bf16* h0 = (__bf16*)(ws + off);  off += (size_t)N * 16 * 2;
    __bf16* h1 = (__bf16*)(ws + off);  off += (size_t)N * 32 * 2;
    __bf16* h2 = (__bf16*)(ws + off);  off += (size_t)N * 64 * 2;
    __bf16* h3 = (__bf16*)(ws + off);  off += (size_t)N * 128 * 2;
    __bf16* h4 = (__bf16*)(ws + off);  off += (size_t)N * 256 * 2;

    cvt_swz_kernel<<<(n_wb + 255) / 256, 256, 0, stream>>>(w1, w2, w3, fc1_w, fc2_w,
                                                           w1b, w2b, w3b, f1b, f2b);
    idxT_kernel<<<(N * 16 + 255) / 256, 256, 0, stream>>>(idx, idxT, N);
    fc0_kernel<<<(N + 255) / 256, 256, 0, stream>>>(x, fc0_w, fc0_b, h0, N);

    // spiral1: 16ch x16 -> 32. TILE 128 (RW=4, CW=1), wave 32x32, NSTEP=4.  [R12]
    mfma_layer<16, 16, 32, 32, 128, 4, 1, true, false, 3, 100000>
        <<<dim3((N + 127) / 128, 1), 256, 0, stream>>>(h0, idxT, w1b, b1, h1);
    // spiral2: 32ch x16 -> 64. TILE 128 (RW=4, CW=1), wave 32x64, NSTEP=8.  [R12]
    mfma_layer<32, 16, 64, 64, 128, 4, 1, true, false, 3, 100000>
        <<<dim3((N + 127) / 128, 1), 256, 0, stream>>>(h1, idxT, w2b, b2, h2);
    // spiral3: 64ch x16 -> 128. TILE 64 (RW=2, CW=2), SHARED-A pairs, 16 KB LDS. [NEW]
    mfma_layer<64, 16, 128, 128, 64, 2, 2, true, true, 3, 100000>
        <<<dim3((N + 63) / 64, 1), 256, 0, stream>>>(h2, idxT, w3b, b3, h3);
    // fc1: dense 128 -> 256, 2 column-blocks of 128. TILE 64, NSTEP=2.      [R12]
    mfma_layer<128, 1, 128, 256, 64, 2, 2, false, false, 4, 100000>
        <<<dim3((N + 63) / 64, 2), 256, 0, stream>>>(h3, nullptr, f1b, fc1_b, h4);
    // fc2 + log_softmax
    fc2_kernel<<<(N + 31) / 32, 256, 0, stream>>>(h4, f2b, fc2_b, out, N);
}

// Round 14
// 269.461 us; speedup vs baseline: 1.0182x; 1.0182x over previous
//
#include <hip/hip_runtime.h>
#include <math.h>
#include <utility>

// N = 100000 nodes, SEQ = 16, layers: 3 ->16 ->32 ->64 ->128 ->256 ->12(log_softmax)
// Spiral layers (R12-proven): bf16 MFMA, barrier-free K-loop, depth-1 gather pipeline,
//   per-wave double-buffered LDS A staging via global_load_lds, exact manual vmcnt.
// NEW (R14): fc1+fc2 FUSED — h4 (51 MB) never touches global memory. One block =
//   32 rows x 256 cols (grid 3125), K=128 staged once in prologue, h4 tile in LDS,
//   fc2 dot + log_softmax on the tile in the same block.
// Evidence base: spiral3 pinned at 64-68 us / FETCH 80.4 MB / ~1.2 TB/s across R8-R13
//   structural variants -> saturated L2-miss fabric path for the random row gather.

typedef __bf16 bf16x8 __attribute__((ext_vector_type(8)));
typedef float f32x16 __attribute__((ext_vector_type(16)));

template <int V> using ic = std::integral_constant<int, V>;

template <typename F, int... Is>
__device__ __forceinline__ void static_for_impl(F&& f, std::integer_sequence<int, Is...>) {
    (f(ic<Is>{}), ...);
}
template <int N_, typename F>
__device__ __forceinline__ void static_for(F&& f) {
    static_for_impl(static_cast<F&&>(f), std::make_integer_sequence<int, N_>{});
}

template <int N_>
__device__ __forceinline__ void wait_vmcnt() {
    static_assert(N_ <= 63, "vmcnt range");
    // gfx9 encoding: vmcnt[3:0] | expcnt<<4 | lgkmcnt<<8 | vmcnt[5:4]<<14 (exp/lgkm = no-wait)
    __builtin_amdgcn_s_waitcnt((N_ & 0xF) | (0x7 << 4) | (0xF << 8) | ((N_ >> 4) << 14));
}

// fence: pin VMEM/DS order, allow ALU/SALU/MFMA to cross
__device__ __forceinline__ void memfence_sched() { __builtin_amdgcn_sched_barrier(0x000F); }

__device__ __forceinline__ float elu_f(float v) { return v > 0.f ? v : expm1f(v); }

// ------------------------------------------------ weight prep: fp32 -> bf16, frag-major swizzle
// dst chunk ((k/64)*8 + (k%64)/8)*COUT + col, element k%8  <-  src[col*K + k]
template <int K, int C>
__device__ __forceinline__ void swz_one(const float* __restrict__ src, __bf16* __restrict__ dst, int j)
{
    int col = j / K;          // K is pow2
    int k = j & (K - 1);
    int chunk = ((k >> 6) * 8 + ((k & 63) >> 3)) * C + col;
    dst[chunk * 8 + (k & 7)] = (__bf16)src[j];
}

__global__ __launch_bounds__(256) void cvt_swz_kernel(const float* __restrict__ w1,
                                                      const float* __restrict__ w2,
                                                      const float* __restrict__ w3,
                                                      const float* __restrict__ f1,
                                                      const float* __restrict__ f2,
                                                      __bf16* __restrict__ d1,
                                                      __bf16* __restrict__ d2,
                                                      __bf16* __restrict__ d3,
                                                      __bf16* __restrict__ df1,
                                                      __bf16* __restrict__ df2)
{
    int i = blockIdx.x * 256 + threadIdx.x;
    if (i < 8192)        swz_one<256, 32>(w1, d1, i);
    else if (i < 40960)  swz_one<512, 64>(w2, d2, i - 8192);
    else if (i < 172032) swz_one<1024, 128>(w3, d3, i - 40960);
    else if (i < 204800) swz_one<128, 256>(f1, df1, i - 172032);
    else if (i < 207872) df2[i - 204800] = (__bf16)f2[i - 204800];   // fc2 stays row-major
}

// ------------------------------------------------ idx transpose: idxT[s*N + n] = idx[n*16 + s]
__global__ __launch_bounds__(256) void idxT_kernel(const int* __restrict__ idx,
                                                   int* __restrict__ idxT, int N)
{
    int i = blockIdx.x * 256 + threadIdx.x;
    if (i >= N * 16) return;
    int n = i >> 4, s = i & 15;
    idxT[s * N + n] = idx[i];
}

// ---------------------------------------------------------------- fc0: [N,3] -> [N,16] bf16
__global__ __launch_bounds__(256) void fc0_kernel(const float* __restrict__ x,
                                                  const float* __restrict__ w,
                                                  const float* __restrict__ b,
                                                  __bf16* __restrict__ h0, int N)
{
    int n = blockIdx.x * 256 + threadIdx.x;
    if (n >= N) return;
    float x0 = x[n * 3 + 0], x1 = x[n * 3 + 1], x2 = x[n * 3 + 2];
    __bf16 ob[16];
#pragma unroll
    for (int j = 0; j < 16; ++j)
        ob[j] = (__bf16)elu_f(w[j * 3 + 0] * x0 + w[j * 3 + 1] * x1 + w[j * 3 + 2] * x2 + b[j]);
    int4* dst = (int4*)&h0[(size_t)n * 16];
    dst[0] = *(int4*)&ob[0];
    dst[1] = *(int4*)&ob[8];
}

// ------------------------------------------- depth-1 pipelined MFMA gather-GEMM (R12)
template <int CIN, int S, int COUT_B, int COUT_TOT, int TILE_M, int RW, int CW,
          bool GATHER, int MINW, int NN>
__global__ __launch_bounds__(256, MINW) void mfma_layer(const __bf16* __restrict__ hin,
                                                        const int* __restrict__ idxT,
                                                        const __bf16* __restrict__ Wsw,
                                                        const float* __restrict__ bias,
                                                        __bf16* __restrict__ hout)
{
    constexpr int K = CIN * S;
    constexpr int NSTEP = K / 64;
    static_assert(K % 64 == 0, "K%64");
    constexpr int WM = TILE_M / RW;        // rows per wave
    constexpr int WN = COUT_B / CW;
    constexpr int MT = WM / 32;            // row subtiles per wave
    constexpr int NT = WN / 32;
    constexpr int IPS = GATHER ? (64 / CIN) : 1;
    constexpr int D = WM / 8;              // DMA insts per step per wave
    constexpr int Bn = NT * 4;             // B vmem loads per step
    constexpr int I = GATHER ? D : 0;      // idx vmem loads per step
    constexpr int NBUFS = 2;
    static_assert(RW * CW == 4, "4 waves");
    static_assert(WM == 32 || WM == 64, "1-2 row subtiles per wave");

    constexpr int AB = 4 * NBUFS * WM * 128;              // A staging bytes
    constexpr int CB = TILE_M * (COUT_B + 8) * 2;         // epilogue staging bytes
    constexpr int SH = AB > CB ? AB : CB;
    __shared__ __align__(16) char smem[SH];

    const int tid = threadIdx.x;
    const int lane = tid & 63;
    const int w = tid >> 6;
    const int wr = w / CW;
    const int wc = w % CW;
    const int ml = lane & 31;
    const int kh = lane >> 5;
    const int m0 = blockIdx.x * TILE_M;
    const int col0 = blockIdx.y * COUT_B;
    const int rbase = m0 + wr * WM;

    char* const Aw = smem + w * (NBUFS * WM * 128);   // this wave's A double buffer

    // ---- per-lane DMA geometry (computed once)
    int ioff[GATHER ? D : 1];
    int koff[GATHER ? D : 1];
    int gmr[GATHER ? 1 : D];
    int coff[GATHER ? 1 : D];
#pragma unroll
    for (int i = 0; i < D; ++i) {
        int r = i * 8 + (lane >> 3);
        int c = (lane & 7) ^ (r & 7);
        int gm = rbase + r; if (gm >= NN) gm = NN - 1;
        if constexpr (GATHER) {
            ioff[i] = ((c * 8) / CIN) * NN + gm;
            koff[i] = (c * 8) & (CIN - 1);
        } else {
            gmr[i] = gm;
            coff[i] = c * 8;
        }
    }

    bf16x8 bfr[2][NT][4];
    int myIdx[GATHER ? 3 : 1][GATHER ? D : 1];

    const __bf16* wlane = Wsw + ((size_t)(col0 + wc * WN + ml) + (size_t)kh * COUT_TOT) * 8;

    auto loadB = [&](auto sc) {
        constexpr int s = decltype(sc)::value;
        if constexpr (s < NSTEP) {
#pragma unroll
            for (int ni = 0; ni < NT; ++ni)
#pragma unroll
                for (int ks = 0; ks < 4; ++ks)
                    bfr[s & 1][ni][ks] = *(const bf16x8*)(wlane
                        + (size_t)(s * 8 + ks * 2) * COUT_TOT * 8 + ni * 32 * 8);
        }
    };
    auto loadIdxS = [&](auto sc) {
        constexpr int s = decltype(sc)::value;
        if constexpr (GATHER && s < NSTEP) {
#pragma unroll
            for (int i = 0; i < D; ++i)
                myIdx[s % 3][i] = idxT[(s * IPS) * NN + ioff[i]];
        }
    };
    auto issueDMA = [&](auto sc) {
        constexpr int s = decltype(sc)::value;
        if constexpr (s < NSTEP) {
            char* base = Aw + (s % NBUFS) * (WM * 128);
#pragma unroll
            for (int i = 0; i < D; ++i) {
                const __bf16* src;
                if constexpr (GATHER)
                    src = hin + (size_t)myIdx[s % 3][i] * CIN + koff[i];
                else
                    src = hin + (size_t)gmr[i] * K + s * 64 + coff[i];
                __builtin_amdgcn_global_load_lds(
                    (const __attribute__((address_space(1))) void*)src,
                    (__attribute__((address_space(3))) void*)(base + i * 1024),
                    16, 0, 0);
            }
        }
    };

    f32x16 acc[MT][NT];
#pragma unroll
    for (int mi = 0; mi < MT; ++mi)
#pragma unroll
        for (int ni = 0; ni < NT; ++ni) { f32x16 z = {}; acc[mi][ni] = z; }

    // ---- prologue (mirrors in-loop group order so vmcnt counts stay exact)
    loadIdxS(ic<0>{});
    loadIdxS(ic<1>{});
    memfence_sched();
    loadB(ic<0>{});
    memfence_sched();
    issueDMA(ic<0>{});
    memfence_sched();
    loadIdxS(ic<2>{});
    memfence_sched();

    // ---- K-loop: [B(s+1)] [DMA(s+1)] [idx(s+3)] | wait DMA(s) | ds_read + MFMA
    static_for<NSTEP>([&](auto sc) {
        constexpr int s = decltype(sc)::value;
        loadB(ic<s + 1>{});
        memfence_sched();
        issueDMA(ic<s + 1>{});
        memfence_sched();
        loadIdxS(ic<s + 3>{});
        memfence_sched();
        constexpr int NW = I * (s + 2 < NSTEP) + (Bn + D) * (s + 1 < NSTEP)
                         + I * (s + 3 < NSTEP);
        wait_vmcnt<NW>();                      // A(s) resident in this wave's LDS buf
        memfence_sched();

        const char* base = Aw + (s % NBUFS) * (WM * 128);
        bf16x8 afr[MT][4];
#pragma unroll
        for (int mi = 0; mi < MT; ++mi)
#pragma unroll
            for (int ks = 0; ks < 4; ++ks) {
                int cb = ks * 2 + kh;
                afr[mi][ks] = *(const bf16x8*)(base + ((mi * 32 + ml) * 8 + (cb ^ (ml & 7))) * 16);
            }
#pragma unroll
        for (int ks = 0; ks < 4; ++ks)
#pragma unroll
            for (int mi = 0; mi < MT; ++mi)
#pragma unroll
                for (int ni = 0; ni < NT; ++ni)
                    acc[mi][ni] = __builtin_amdgcn_mfma_f32_32x32x16_bf16(
                        afr[mi][ks], bfr[s & 1][ni][ks], acc[mi][ni], 0, 0, 0);
    });

    // ---- epilogue: acc -> LDS (reuse A region) -> coalesced int4 stores
    __syncthreads();
    __bf16* Cs = (__bf16*)smem;
    constexpr int LDC = COUT_B + 8;
#pragma unroll
    for (int ni = 0; ni < NT; ++ni) {
        const int col = wc * WN + ni * 32 + ml;
        const float bv = bias[col0 + col];
#pragma unroll
        for (int mi = 0; mi < MT; ++mi) {
#pragma unroll
            for (int r = 0; r < 16; ++r) {
                int row = wr * WM + mi * 32 + ((r & 3) + 8 * (r >> 2) + 4 * kh);
                Cs[row * LDC + col] = (__bf16)elu_f(acc[mi][ni][r] + bv);
            }
        }
    }
    __syncthreads();
    constexpr int C8 = COUT_B / 8;
#pragma unroll
    for (int j2 = tid; j2 < TILE_M * C8; j2 += 256) {
        int row = j2 / C8, c8 = j2 % C8;
        int gm = m0 + row;
        if (gm < NN)
            *(int4*)&hout[(size_t)gm * COUT_TOT + col0 + c8 * 8] = *(int4*)&Cs[row * LDC + c8 * 8];
    }
}

// ------------------------------------------- FUSED fc1 + fc2 + log_softmax
// Block: 32 rows x 256 cols of h4 (K=128); h4 tile lives only in LDS.
// Wave w computes cols w*64..w*64+63 (NT=2), then fc2 on rows w*8..w*8+7.
__global__ __launch_bounds__(256, 3) void fc12_kernel(const __bf16* __restrict__ h3,   // [N,128]
                                                      const __bf16* __restrict__ Wsw,  // fc1 frag-major (K=128,C=256)
                                                      const float* __restrict__ bias1, // [256]
                                                      const __bf16* __restrict__ W2,   // [12,256] row-major
                                                      const float* __restrict__ bias2, // [12]
                                                      float* __restrict__ out)
{
    __shared__ __align__(16) char smem[32 * 264 * 2];   // 16.9 KB: A (8 KB) then h4 tile
    const int tid = threadIdx.x;
    const int lane = tid & 63;
    const int w = tid >> 6;
    const int ml = lane & 31;
    const int kh = lane >> 5;
    const int c = lane & 31;
    const int m0 = blockIdx.x * 32;

    // fc2 weights -> regs (12 x 16B per lane)
    bf16x8 wreg[12];
#pragma unroll
    for (int o = 0; o < 12; ++o) wreg[o] = *(const bf16x8*)&W2[o * 256 + c * 8];

    // fc1 B fragments: wave w covers cols w*64 .. w*64+63
    const __bf16* wlane = Wsw + ((size_t)(w * 64 + ml) + (size_t)kh * 256) * 8;
    bf16x8 bfr[2][2][4];
#pragma unroll
    for (int s = 0; s < 2; ++s)
#pragma unroll
        for (int ni = 0; ni < 2; ++ni)
#pragma unroll
            for (int ks = 0; ks < 4; ++ks)
                bfr[s][ni][ks] = *(const bf16x8*)(wlane
                    + (size_t)(s * 8 + ks * 2) * 256 * 8 + ni * 32 * 8);

    // stage A: 32 rows x 128 ch bf16 = 8 KB, 2 DMA insts per wave, XOR swizzle at source
#pragma unroll
    for (int t = 0; t < 2; ++t) {
        int j = w * 2 + t;
        int lr = j * 4 + (lane >> 4);          // local row 0..31
        int sc = (lane & 15) ^ (lr & 15);      // source 16B chunk (XOR swizzle)
        const __bf16* src = h3 + (size_t)(m0 + lr) * 128 + sc * 8;
        __builtin_amdgcn_global_load_lds(
            (const __attribute__((address_space(1))) void*)src,
            (__attribute__((address_space(3))) void*)(smem + j * 1024),
            16, 0, 0);
    }
    wait_vmcnt<0>();
    __syncthreads();

    // fc1 MFMAs (K=128, 2 steps, A shared by all waves)
    f32x16 acc[2];
    { f32x16 z = {}; acc[0] = z; acc[1] = z; }
    const char* Ab = smem;
#pragma unroll
    for (int s = 0; s < 2; ++s) {
        bf16x8 afr[4];
#pragma unroll
        for (int ks = 0; ks < 4; ++ks) {
            int c16 = s * 8 + ks * 2 + kh;
            afr[ks] = *(const bf16x8*)(Ab + ml * 256 + ((c16 ^ (ml & 15)) * 16));
        }
#pragma unroll
        for (int ks = 0; ks < 4; ++ks)
#pragma unroll
            for (int ni = 0; ni < 2; ++ni)
                acc[ni] = __builtin_amdgcn_mfma_f32_32x32x16_bf16(afr[ks], bfr[s][ni][ks], acc[ni], 0, 0, 0);
    }
    __syncthreads();   // all waves done reading A before tile overwrite

    // h4 tile (bias + ELU, bf16 to match previous numerics), LDC = 264
    __bf16* Cs = (__bf16*)smem;
#pragma unroll
    for (int ni = 0; ni < 2; ++ni) {
        int col = w * 64 + ni * 32 + ml;
        float bv = bias1[col];
#pragma unroll
        for (int r = 0; r < 16; ++r) {
            int row = (r & 3) + 8 * (r >> 2) + 4 * kh;
            Cs[row * 264 + col] = (__bf16)elu_f(acc[ni][r] + bv);
        }
    }
    __syncthreads();

    // fc2 + log_softmax: wave w handles rows w*8..w*8+7, 2 rows per pass (half-waves)
    const int half = lane >> 5;
#pragma unroll
    for (int p = 0; p < 4; ++p) {
        int nl = w * 8 + p * 2 + half;
        bf16x8 h = *(const bf16x8*)&Cs[nl * 264 + c * 8];
        float hf[8];
#pragma unroll
        for (int j = 0; j < 8; ++j) hf[j] = (float)h[j];
        float pr[12];
#pragma unroll
        for (int o = 0; o < 12; ++o) {
            float s = 0.f;
#pragma unroll
            for (int j = 0; j < 8; ++j) s += hf[j] * (float)wreg[o][j];
            pr[o] = s;
        }
#pragma unroll
        for (int off = 16; off > 0; off >>= 1) {
#pragma unroll
            for (int o = 0; o < 12; ++o) pr[o] += __shfl_down(pr[o], off, 32);
        }
        if (c == 0) {
            float logits[12], mx = -1e30f;
#pragma unroll
            for (int o = 0; o < 12; ++o) {
                logits[o] = pr[o] + bias2[o];
                mx = fmaxf(mx, logits[o]);
            }
            float s = 0.f;
#pragma unroll
            for (int o = 0; o < 12; ++o) s += expf(logits[o] - mx);
            float lse = mx + logf(s);
            int n = m0 + nl;
            float4 o0 = make_float4(logits[0] - lse, logits[1] - lse, logits[2] - lse, logits[3] - lse);
            float4 o1 = make_float4(logits[4] - lse, logits[5] - lse, logits[6] - lse, logits[7] - lse);
            float4 o2 = make_float4(logits[8] - lse, logits[9] - lse, logits[10] - lse, logits[11] - lse);
            *(float4*)&out[(size_t)n * 12 + 0] = o0;
            *(float4*)&out[(size_t)n * 12 + 4] = o1;
            *(float4*)&out[(size_t)n * 12 + 8] = o2;
        }
    }
}

extern "C" void kernel_launch(void* const* d_in, const int* in_sizes, int n_in,
                              void* d_out, int out_size, void* d_ws, size_t ws_size,
                              hipStream_t stream)
{
    const int N = 100000;
    const float* x     = (const float*)d_in[0];
    const int*   idx   = (const int*)  d_in[1];
    const float* fc0_w = (const float*)d_in[2];
    const float* fc0_b = (const float*)d_in[3];
    const float* w1    = (const float*)d_in[4];
    const float* b1    = (const float*)d_in[5];
    const float* w2    = (const float*)d_in[6];
    const float* b2    = (const float*)d_in[7];
    const float* w3    = (const float*)d_in[8];
    const float* b3    = (const float*)d_in[9];
    const float* fc1_w = (const float*)d_in[10];
    const float* fc1_b = (const float*)d_in[11];
    const float* fc2_w = (const float*)d_in[12];
    const float* fc2_b = (const float*)d_in[13];
    float* out = (float*)d_out;

    // ---- workspace layout
    char* ws = (char*)d_ws;
    const int n_w1 = 32 * 256, n_w2 = 64 * 512, n_w3 = 128 * 1024, n_fc1 = 256 * 128, n_fc2 = 12 * 256;
    const int n_wb = n_w1 + n_w2 + n_w3 + n_fc1 + n_fc2;   // 207872
    __bf16* w1b = (__bf16*)ws;
    __bf16* w2b = w1b + n_w1;
    __bf16* w3b = w2b + n_w2;
    __bf16* f1b = w3b + n_w3;
    __bf16* f2b = f1b + n_fc1;
    size_t off = ((size_t)n_wb * 2 + 4095) & ~(size_t)4095;
    int* idxT = (int*)(ws + off);      off += (size_t)N * 16 * 4;
    __bf16* h0 = (__bf16*)(ws + off);  off += (size_t)N * 16 * 2;
    __bf16* h1 = (__bf16*)(ws + off);  off += (size_t)N * 32 * 2;
    __bf16* h2 = (__bf16*)(ws + off);  off += (size_t)N * 64 * 2;
    __bf16* h3 = (__bf16*)(ws + off);  off += (size_t)N * 128 * 2;

    cvt_swz_kernel<<<(n_wb + 255) / 256, 256, 0, stream>>>(w1, w2, w3, fc1_w, fc2_w,
                                                           w1b, w2b, w3b, f1b, f2b);
    idxT_kernel<<<(N * 16 + 255) / 256, 256, 0, stream>>>(idx, idxT, N);
    fc0_kernel<<<(N + 255) / 256, 256, 0, stream>>>(x, fc0_w, fc0_b, h0, N);

    // spiral1: 16ch x16 -> 32. TILE 128 (RW=4, CW=1), wave 32x32, NSTEP=4.  [R12]
    mfma_layer<16, 16, 32, 32, 128, 4, 1, true, 3, 100000>
        <<<dim3((N + 127) / 128, 1), 256, 0, stream>>>(h0, idxT, w1b, b1, h1);
    // spiral2: 32ch x16 -> 64. TILE 128 (RW=4, CW=1), wave 32x64, NSTEP=8.  [R12]
    mfma_layer<32, 16, 64, 64, 128, 4, 1, true, 3, 100000>
        <<<dim3((N + 127) / 128, 1), 256, 0, stream>>>(h1, idxT, w2b, b2, h2);
    // spiral3: 64ch x16 -> 128. TILE 64 (RW=2, CW=2), wave 32x64, NSTEP=16. [R12]
    mfma_layer<64, 16, 128, 128, 64, 2, 2, true, 3, 100000>
        <<<dim3((N + 63) / 64, 1), 256, 0, stream>>>(h2, idxT, w3b, b3, h3);
    // FUSED fc1 + fc2 + log_softmax: 32 rows/block, h4 in LDS only. [NEW]
    fc12_kernel<<<N / 32, 256, 0, stream>>>(h3, f1b, fc1_b, f2b, fc2_b, out);
}

// Round 15
// 228.853 us; speedup vs baseline: 1.1989x; 1.1774x over previous
//
#include <hip/hip_runtime.h>
#include <math.h>
#include <utility>

// N = 100000 nodes, SEQ = 16, layers: 3 ->16 ->32 ->64 ->128 ->256 ->12(log_softmax)
// Spiral layers (R12-proven): bf16 MFMA, barrier-free K-loop, depth-1 gather pipeline,
//   per-wave double-buffered LDS A staging via global_load_lds, exact manual vmcnt.
// fc1+fc2+log_softmax FUSED (R15): h4 lives only in LDS. fc2 now runs on MFMA:
//   W2 padded to 32 cols (frag-major, zero-filled); each wave does a split-K 32x32
//   partial (4 MFMAs) on its own k-slice of the h4 tile; partials tree-summed in LDS;
//   log_softmax on 32 parallel lanes of wave 0 (no divergence, no scalar dots).
// Evidence base: R14 fc12 was VALUBusy=60% from scalar fc2 dots + divergent softmax.

typedef __bf16 bf16x8 __attribute__((ext_vector_type(8)));
typedef float f32x16 __attribute__((ext_vector_type(16)));

template <int V> using ic = std::integral_constant<int, V>;

template <typename F, int... Is>
__device__ __forceinline__ void static_for_impl(F&& f, std::integer_sequence<int, Is...>) {
    (f(ic<Is>{}), ...);
}
template <int N_, typename F>
__device__ __forceinline__ void static_for(F&& f) {
    static_for_impl(static_cast<F&&>(f), std::make_integer_sequence<int, N_>{});
}

template <int N_>
__device__ __forceinline__ void wait_vmcnt() {
    static_assert(N_ <= 63, "vmcnt range");
    // gfx9 encoding: vmcnt[3:0] | expcnt<<4 | lgkmcnt<<8 | vmcnt[5:4]<<14 (exp/lgkm = no-wait)
    __builtin_amdgcn_s_waitcnt((N_ & 0xF) | (0x7 << 4) | (0xF << 8) | ((N_ >> 4) << 14));
}

// fence: pin VMEM/DS order, allow ALU/SALU/MFMA to cross
__device__ __forceinline__ void memfence_sched() { __builtin_amdgcn_sched_barrier(0x000F); }

__device__ __forceinline__ float elu_f(float v) { return v > 0.f ? v : expm1f(v); }

// ------------------------------------------------ weight prep: fp32 -> bf16, frag-major swizzle
// dst chunk ((k/64)*8 + (k%64)/8)*COUT + col, element k%8  <-  src[col*K + k]
template <int K, int C>
__device__ __forceinline__ void swz_one(const float* __restrict__ src, __bf16* __restrict__ dst, int j)
{
    int col = j / K;          // K is pow2
    int k = j & (K - 1);
    int chunk = ((k >> 6) * 8 + ((k & 63) >> 3)) * C + col;
    dst[chunk * 8 + (k & 7)] = (__bf16)src[j];
}

__global__ __launch_bounds__(256) void cvt_swz_kernel(const float* __restrict__ w1,
                                                      const float* __restrict__ w2,
                                                      const float* __restrict__ w3,
                                                      const float* __restrict__ f1,
                                                      const float* __restrict__ f2,
                                                      __bf16* __restrict__ d1,
                                                      __bf16* __restrict__ d2,
                                                      __bf16* __restrict__ d3,
                                                      __bf16* __restrict__ df1,
                                                      __bf16* __restrict__ df2p)
{
    int i = blockIdx.x * 256 + threadIdx.x;
    if (i < 8192)        swz_one<256, 32>(w1, d1, i);
    else if (i < 40960)  swz_one<512, 64>(w2, d2, i - 8192);
    else if (i < 172032) swz_one<1024, 128>(w3, d3, i - 40960);
    else if (i < 204800) swz_one<128, 256>(f1, df1, i - 172032);
    else if (i < 212992) {
        // fc2 padded to 32 cols, frag-major (K=256, C=32); inverse map over DEST index
        int d = i - 204800;                 // 0 .. 8191
        int e = d & 7;
        int chunkIdx = d >> 3;
        int col = chunkIdx & 31;
        int q = chunkIdx >> 5;
        int k = (q >> 3) * 64 + (q & 7) * 8 + e;
        df2p[d] = (col < 12) ? (__bf16)f2[col * 256 + k] : (__bf16)0.f;
    }
}

// ------------------------------------------------ idx transpose: idxT[s*N + n] = idx[n*16 + s]
__global__ __launch_bounds__(256) void idxT_kernel(const int* __restrict__ idx,
                                                   int* __restrict__ idxT, int N)
{
    int i = blockIdx.x * 256 + threadIdx.x;
    if (i >= N * 16) return;
    int n = i >> 4, s = i & 15;
    idxT[s * N + n] = idx[i];
}

// ---------------------------------------------------------------- fc0: [N,3] -> [N,16] bf16
__global__ __launch_bounds__(256) void fc0_kernel(const float* __restrict__ x,
                                                  const float* __restrict__ w,
                                                  const float* __restrict__ b,
                                                  __bf16* __restrict__ h0, int N)
{
    int n = blockIdx.x * 256 + threadIdx.x;
    if (n >= N) return;
    float x0 = x[n * 3 + 0], x1 = x[n * 3 + 1], x2 = x[n * 3 + 2];
    __bf16 ob[16];
#pragma unroll
    for (int j = 0; j < 16; ++j)
        ob[j] = (__bf16)elu_f(w[j * 3 + 0] * x0 + w[j * 3 + 1] * x1 + w[j * 3 + 2] * x2 + b[j]);
    int4* dst = (int4*)&h0[(size_t)n * 16];
    dst[0] = *(int4*)&ob[0];
    dst[1] = *(int4*)&ob[8];
}

// ------------------------------------------- depth-1 pipelined MFMA gather-GEMM (R12)
template <int CIN, int S, int COUT_B, int COUT_TOT, int TILE_M, int RW, int CW,
          bool GATHER, int MINW, int NN>
__global__ __launch_bounds__(256, MINW) void mfma_layer(const __bf16* __restrict__ hin,
                                                        const int* __restrict__ idxT,
                                                        const __bf16* __restrict__ Wsw,
                                                        const float* __restrict__ bias,
                                                        __bf16* __restrict__ hout)
{
    constexpr int K = CIN * S;
    constexpr int NSTEP = K / 64;
    static_assert(K % 64 == 0, "K%64");
    constexpr int WM = TILE_M / RW;        // rows per wave
    constexpr int WN = COUT_B / CW;
    constexpr int MT = WM / 32;            // row subtiles per wave
    constexpr int NT = WN / 32;
    constexpr int IPS = GATHER ? (64 / CIN) : 1;
    constexpr int D = WM / 8;              // DMA insts per step per wave
    constexpr int Bn = NT * 4;             // B vmem loads per step
    constexpr int I = GATHER ? D : 0;      // idx vmem loads per step
    constexpr int NBUFS = 2;
    static_assert(RW * CW == 4, "4 waves");
    static_assert(WM == 32 || WM == 64, "1-2 row subtiles per wave");

    constexpr int AB = 4 * NBUFS * WM * 128;              // A staging bytes
    constexpr int CB = TILE_M * (COUT_B + 8) * 2;         // epilogue staging bytes
    constexpr int SH = AB > CB ? AB : CB;
    __shared__ __align__(16) char smem[SH];

    const int tid = threadIdx.x;
    const int lane = tid & 63;
    const int w = tid >> 6;
    const int wr = w / CW;
    const int wc = w % CW;
    const int ml = lane & 31;
    const int kh = lane >> 5;
    const int m0 = blockIdx.x * TILE_M;
    const int col0 = blockIdx.y * COUT_B;
    const int rbase = m0 + wr * WM;

    char* const Aw = smem + w * (NBUFS * WM * 128);   // this wave's A double buffer

    // ---- per-lane DMA geometry (computed once)
    int ioff[GATHER ? D : 1];
    int koff[GATHER ? D : 1];
    int gmr[GATHER ? 1 : D];
    int coff[GATHER ? 1 : D];
#pragma unroll
    for (int i = 0; i < D; ++i) {
        int r = i * 8 + (lane >> 3);
        int c = (lane & 7) ^ (r & 7);
        int gm = rbase + r; if (gm >= NN) gm = NN - 1;
        if constexpr (GATHER) {
            ioff[i] = ((c * 8) / CIN) * NN + gm;
            koff[i] = (c * 8) & (CIN - 1);
        } else {
            gmr[i] = gm;
            coff[i] = c * 8;
        }
    }

    bf16x8 bfr[2][NT][4];
    int myIdx[GATHER ? 3 : 1][GATHER ? D : 1];

    const __bf16* wlane = Wsw + ((size_t)(col0 + wc * WN + ml) + (size_t)kh * COUT_TOT) * 8;

    auto loadB = [&](auto sc) {
        constexpr int s = decltype(sc)::value;
        if constexpr (s < NSTEP) {
#pragma unroll
            for (int ni = 0; ni < NT; ++ni)
#pragma unroll
                for (int ks = 0; ks < 4; ++ks)
                    bfr[s & 1][ni][ks] = *(const bf16x8*)(wlane
                        + (size_t)(s * 8 + ks * 2) * COUT_TOT * 8 + ni * 32 * 8);
        }
    };
    auto loadIdxS = [&](auto sc) {
        constexpr int s = decltype(sc)::value;
        if constexpr (GATHER && s < NSTEP) {
#pragma unroll
            for (int i = 0; i < D; ++i)
                myIdx[s % 3][i] = idxT[(s * IPS) * NN + ioff[i]];
        }
    };
    auto issueDMA = [&](auto sc) {
        constexpr int s = decltype(sc)::value;
        if constexpr (s < NSTEP) {
            char* base = Aw + (s % NBUFS) * (WM * 128);
#pragma unroll
            for (int i = 0; i < D; ++i) {
                const __bf16* src;
                if constexpr (GATHER)
                    src = hin + (size_t)myIdx[s % 3][i] * CIN + koff[i];
                else
                    src = hin + (size_t)gmr[i] * K + s * 64 + coff[i];
                __builtin_amdgcn_global_load_lds(
                    (const __attribute__((address_space(1))) void*)src,
                    (__attribute__((address_space(3))) void*)(base + i * 1024),
                    16, 0, 0);
            }
        }
    };

    f32x16 acc[MT][NT];
#pragma unroll
    for (int mi = 0; mi < MT; ++mi)
#pragma unroll
        for (int ni = 0; ni < NT; ++ni) { f32x16 z = {}; acc[mi][ni] = z; }

    // ---- prologue (mirrors in-loop group order so vmcnt counts stay exact)
    loadIdxS(ic<0>{});
    loadIdxS(ic<1>{});
    memfence_sched();
    loadB(ic<0>{});
    memfence_sched();
    issueDMA(ic<0>{});
    memfence_sched();
    loadIdxS(ic<2>{});
    memfence_sched();

    // ---- K-loop: [B(s+1)] [DMA(s+1)] [idx(s+3)] | wait DMA(s) | ds_read + MFMA
    static_for<NSTEP>([&](auto sc) {
        constexpr int s = decltype(sc)::value;
        loadB(ic<s + 1>{});
        memfence_sched();
        issueDMA(ic<s + 1>{});
        memfence_sched();
        loadIdxS(ic<s + 3>{});
        memfence_sched();
        constexpr int NW = I * (s + 2 < NSTEP) + (Bn + D) * (s + 1 < NSTEP)
                         + I * (s + 3 < NSTEP);
        wait_vmcnt<NW>();                      // A(s) resident in this wave's LDS buf
        memfence_sched();

        const char* base = Aw + (s % NBUFS) * (WM * 128);
        bf16x8 afr[MT][4];
#pragma unroll
        for (int mi = 0; mi < MT; ++mi)
#pragma unroll
            for (int ks = 0; ks < 4; ++ks) {
                int cb = ks * 2 + kh;
                afr[mi][ks] = *(const bf16x8*)(base + ((mi * 32 + ml) * 8 + (cb ^ (ml & 7))) * 16);
            }
#pragma unroll
        for (int ks = 0; ks < 4; ++ks)
#pragma unroll
            for (int mi = 0; mi < MT; ++mi)
#pragma unroll
                for (int ni = 0; ni < NT; ++ni)
                    acc[mi][ni] = __builtin_amdgcn_mfma_f32_32x32x16_bf16(
                        afr[mi][ks], bfr[s & 1][ni][ks], acc[mi][ni], 0, 0, 0);
    });

    // ---- epilogue: acc -> LDS (reuse A region) -> coalesced int4 stores
    __syncthreads();
    __bf16* Cs = (__bf16*)smem;
    constexpr int LDC = COUT_B + 8;
#pragma unroll
    for (int ni = 0; ni < NT; ++ni) {
        const int col = wc * WN + ni * 32 + ml;
        const float bv = bias[col0 + col];
#pragma unroll
        for (int mi = 0; mi < MT; ++mi) {
#pragma unroll
            for (int r = 0; r < 16; ++r) {
                int row = wr * WM + mi * 32 + ((r & 3) + 8 * (r >> 2) + 4 * kh);
                Cs[row * LDC + col] = (__bf16)elu_f(acc[mi][ni][r] + bv);
            }
        }
    }
    __syncthreads();
    constexpr int C8 = COUT_B / 8;
#pragma unroll
    for (int j2 = tid; j2 < TILE_M * C8; j2 += 256) {
        int row = j2 / C8, c8 = j2 % C8;
        int gm = m0 + row;
        if (gm < NN)
            *(int4*)&hout[(size_t)gm * COUT_TOT + col0 + c8 * 8] = *(int4*)&Cs[row * LDC + c8 * 8];
    }
}

// ------------------------------------------- FUSED fc1 + fc2(MFMA) + log_softmax
// Block: 32 rows x 256 cols of h4 (K=128); h4 tile lives only in LDS.
// Wave w: fc1 cols w*64..w*64+63 (NT=2, 8 MFMAs), then fc2 split-K partial on
// k-slice [w*64, w*64+64) (4 MFMAs vs 32-col padded W2), LDS tree-sum, softmax.
__global__ __launch_bounds__(256, 3) void fc12_kernel(const __bf16* __restrict__ h3,   // [N,128]
                                                      const __bf16* __restrict__ Wsw,  // fc1 frag-major (K=128,C=256)
                                                      const float* __restrict__ bias1, // [256]
                                                      const __bf16* __restrict__ W2p,  // fc2 frag-major padded (K=256,C=32)
                                                      const float* __restrict__ bias2, // [12]
                                                      float* __restrict__ out)
{
    __shared__ __align__(16) char smem[32 * 264 * 2];   // 16.9 KB: A (8 KB) / h4 tile / partials
    const int tid = threadIdx.x;
    const int lane = tid & 63;
    const int w = tid >> 6;
    const int ml = lane & 31;
    const int kh = lane >> 5;
    const int m0 = blockIdx.x * 32;

    // fc1 B fragments: wave w covers cols w*64 .. w*64+63
    const __bf16* wlane = Wsw + ((size_t)(w * 64 + ml) + (size_t)kh * 256) * 8;
    bf16x8 bfr[2][2][4];
#pragma unroll
    for (int s = 0; s < 2; ++s)
#pragma unroll
        for (int ni = 0; ni < 2; ++ni)
#pragma unroll
            for (int ks = 0; ks < 4; ++ks)
                bfr[s][ni][ks] = *(const bf16x8*)(wlane
                    + (size_t)(s * 8 + ks * 2) * 256 * 8 + ni * 32 * 8);

    // fc2 B fragments: wave w's k-slice [w*64, w*64+64), cols 0..31 (12 real + 20 zero)
    bf16x8 b2f[4];
#pragma unroll
    for (int ks = 0; ks < 4; ++ks)
        b2f[ks] = *(const bf16x8*)&W2p[((w * 8 + ks * 2 + kh) * 32 + ml) * 8];

    // stage A: 32 rows x 128 ch bf16 = 8 KB, 2 DMA insts per wave, XOR swizzle at source
#pragma unroll
    for (int t = 0; t < 2; ++t) {
        int j = w * 2 + t;
        int lr = j * 4 + (lane >> 4);          // local row 0..31
        int sc = (lane & 15) ^ (lr & 15);      // source 16B chunk (XOR swizzle)
        const __bf16* src = h3 + (size_t)(m0 + lr) * 128 + sc * 8;
        __builtin_amdgcn_global_load_lds(
            (const __attribute__((address_space(1))) void*)src,
            (__attribute__((address_space(3))) void*)(smem + j * 1024),
            16, 0, 0);
    }
    wait_vmcnt<0>();
    __syncthreads();

    // fc1 MFMAs (K=128, 2 steps, A shared by all waves)
    f32x16 acc[2];
    { f32x16 z = {}; acc[0] = z; acc[1] = z; }
    const char* Ab = smem;
#pragma unroll
    for (int s = 0; s < 2; ++s) {
        bf16x8 afr[4];
#pragma unroll
        for (int ks = 0; ks < 4; ++ks) {
            int c16 = s * 8 + ks * 2 + kh;
            afr[ks] = *(const bf16x8*)(Ab + ml * 256 + ((c16 ^ (ml & 15)) * 16));
        }
#pragma unroll
        for (int ks = 0; ks < 4; ++ks)
#pragma unroll
            for (int ni = 0; ni < 2; ++ni)
                acc[ni] = __builtin_amdgcn_mfma_f32_32x32x16_bf16(afr[ks], bfr[s][ni][ks], acc[ni], 0, 0, 0);
    }
    __syncthreads();   // all waves done reading A before tile overwrite

    // h4 tile (bias + ELU, bf16), LDC = 264 (33x16B row stride -> conflict-free b128)
    __bf16* Cs = (__bf16*)smem;
#pragma unroll
    for (int ni = 0; ni < 2; ++ni) {
        int col = w * 64 + ni * 32 + ml;
        float bv = bias1[col];
#pragma unroll
        for (int r = 0; r < 16; ++r) {
            int row = (r & 3) + 8 * (r >> 2) + 4 * kh;
            Cs[row * 264 + col] = (__bf16)elu_f(acc[ni][r] + bv);
        }
    }
    __syncthreads();

    // ---- fc2 split-K MFMA: wave w reads A2 frags from its k-slice of the tile
    bf16x8 a2[4];
#pragma unroll
    for (int ks = 0; ks < 4; ++ks)
        a2[ks] = *(const bf16x8*)&Cs[ml * 264 + w * 64 + ks * 16 + kh * 8];
    f32x16 acc2;
    { f32x16 z = {}; acc2 = z; }
#pragma unroll
    for (int ks = 0; ks < 4; ++ks)
        acc2 = __builtin_amdgcn_mfma_f32_32x32x16_bf16(a2[ks], b2f[ks], acc2, 0, 0, 0);
    __syncthreads();   // all tile reads retired (a2 consumed by MFMA) before overwrite

    // partial C2 [32x32] f32 -> LDS region w (flat row*32+col layout, conflict-free)
    float* P = (float*)(smem + w * 4096);
#pragma unroll
    for (int r = 0; r < 16; ++r)
        P[((r & 3) + 8 * (r >> 2) + 4 * kh) * 32 + ml] = acc2[r];
    __syncthreads();

    // tree-sum the 4 partials: 256 threads x float4
    float4 s4 = make_float4(0.f, 0.f, 0.f, 0.f);
#pragma unroll
    for (int pw = 0; pw < 4; ++pw) {
        float4 v = *(float4*)(smem + pw * 4096 + tid * 16);
        s4.x += v.x; s4.y += v.y; s4.z += v.z; s4.w += v.w;
    }
    __syncthreads();   // all partial reads done before region-0 overwrite
    *(float4*)(smem + tid * 16) = s4;
    __syncthreads();

    // log_softmax: lanes 0..31 of wave 0, one row each (fully parallel)
    if (tid < 32) {
        const float* L = (float*)smem + tid * 32;
        float logits[12], mx = -1e30f;
#pragma unroll
        for (int o = 0; o < 12; ++o) {
            logits[o] = L[o] + bias2[o];
            mx = fmaxf(mx, logits[o]);
        }
        float s = 0.f;
#pragma unroll
        for (int o = 0; o < 12; ++o) s += expf(logits[o] - mx);
        float lse = mx + logf(s);
        int n = m0 + tid;
        float4 o0 = make_float4(logits[0] - lse, logits[1] - lse, logits[2] - lse, logits[3] - lse);
        float4 o1 = make_float4(logits[4] - lse, logits[5] - lse, logits[6] - lse, logits[7] - lse);
        float4 o2 = make_float4(logits[8] - lse, logits[9] - lse, logits[10] - lse, logits[11] - lse);
        *(float4*)&out[(size_t)n * 12 + 0] = o0;
        *(float4*)&out[(size_t)n * 12 + 4] = o1;
        *(float4*)&out[(size_t)n * 12 + 8] = o2;
    }
}

extern "C" void kernel_launch(void* const* d_in, const int* in_sizes, int n_in,
                              void* d_out, int out_size, void* d_ws, size_t ws_size,
                              hipStream_t stream)
{
    const int N = 100000;
    const float* x     = (const float*)d_in[0];
    const int*   idx   = (const int*)  d_in[1];
    const float* fc0_w = (const float*)d_in[2];
    const float* fc0_b = (const float*)d_in[3];
    const float* w1    = (const float*)d_in[4];
    const float* b1    = (const float*)d_in[5];
    const float* w2    = (const float*)d_in[6];
    const float* b2    = (const float*)d_in[7];
    const float* w3    = (const float*)d_in[8];
    const float* b3    = (const float*)d_in[9];
    const float* fc1_w = (const float*)d_in[10];
    const float* fc1_b = (const float*)d_in[11];
    const float* fc2_w = (const float*)d_in[12];
    const float* fc2_b = (const float*)d_in[13];
    float* out = (float*)d_out;

    // ---- workspace layout
    char* ws = (char*)d_ws;
    const int n_w1 = 32 * 256, n_w2 = 64 * 512, n_w3 = 128 * 1024, n_fc1 = 256 * 128;
    const int n_fc2p = 32 * 256;                            // padded frag-major fc2
    const int n_wb = n_w1 + n_w2 + n_w3 + n_fc1 + n_fc2p;   // 212992
    __bf16* w1b = (__bf16*)ws;
    __bf16* w2b = w1b + n_w1;
    __bf16* w3b = w2b + n_w2;
    __bf16* f1b = w3b + n_w3;
    __bf16* f2b = f1b + n_fc1;
    size_t off = ((size_t)n_wb * 2 + 4095) & ~(size_t)4095;
    int* idxT = (int*)(ws + off);      off += (size_t)N * 16 * 4;
    __bf16* h0 = (__bf16*)(ws + off);  off += (size_t)N * 16 * 2;
    __bf16* h1 = (__bf16*)(ws + off);  off += (size_t)N * 32 * 2;
    __bf16* h2 = (__bf16*)(ws + off);  off += (size_t)N * 64 * 2;
    __bf16* h3 = (__bf16*)(ws + off);  off += (size_t)N * 128 * 2;

    cvt_swz_kernel<<<(n_wb + 255) / 256, 256, 0, stream>>>(w1, w2, w3, fc1_w, fc2_w,
                                                           w1b, w2b, w3b, f1b, f2b);
    idxT_kernel<<<(N * 16 + 255) / 256, 256, 0, stream>>>(idx, idxT, N);
    fc0_kernel<<<(N + 255) / 256, 256, 0, stream>>>(x, fc0_w, fc0_b, h0, N);

    // spiral1: 16ch x16 -> 32. TILE 128 (RW=4, CW=1), wave 32x32, NSTEP=4.  [R12]
    mfma_layer<16, 16, 32, 32, 128, 4, 1, true, 3, 100000>
        <<<dim3((N + 127) / 128, 1), 256, 0, stream>>>(h0, idxT, w1b, b1, h1);
    // spiral2: 32ch x16 -> 64. TILE 128 (RW=4, CW=1), wave 32x64, NSTEP=8.  [R12]
    mfma_layer<32, 16, 64, 64, 128, 4, 1, true, 3, 100000>
        <<<dim3((N + 127) / 128, 1), 256, 0, stream>>>(h1, idxT, w2b, b2, h2);
    // spiral3: 64ch x16 -> 128. TILE 64 (RW=2, CW=2), wave 32x64, NSTEP=16. [R12]
    mfma_layer<64, 16, 128, 128, 64, 2, 2, true, 3, 100000>
        <<<dim3((N + 63) / 64, 1), 256, 0, stream>>>(h2, idxT, w3b, b3, h3);
    // FUSED fc1 + fc2(MFMA) + log_softmax: 32 rows/block, h4 in LDS only. [R15]
    fc12_kernel<<<N / 32, 256, 0, stream>>>(h3, f1b, fc1_b, f2b, fc2_b, out);
}

// Round 17
// 224.889 us; speedup vs baseline: 1.2200x; 1.0176x over previous
//
#include <hip/hip_runtime.h>
#include <hip/hip_fp8.h>
#include <math.h>
#include <utility>

// N = 100000 nodes, SEQ = 16, layers: 3 ->16 ->32 ->64 ->128 ->256 ->12(log_softmax)
// R17 (mixed-precision spiral3): h2 stored fp8 e4m3 (64-B rows -> HALVED random-gather
//   line count), but w3 stays bf16: A fragments are dequantized fp8->bf16 in VGPRs
//   after ds_read, then bf16 MFMA. Only ONE quantization source (h2) vs R16's two
//   (R16 absmax 0.1406 > 0.125; quadrature predicts ~0.10 with w3 exact).
// spiral1/2: R12-proven bf16 depth-1 pipeline (spiral2 epilogue emits fp8 h2).
// fc1+fc2+log_softmax fused with MFMA fc2 (R15-proven).

typedef __bf16 bf16x8 __attribute__((ext_vector_type(8)));
typedef float f32x16 __attribute__((ext_vector_type(16)));

template <int V> using ic = std::integral_constant<int, V>;

template <typename F, int... Is>
__device__ __forceinline__ void static_for_impl(F&& f, std::integer_sequence<int, Is...>) {
    (f(ic<Is>{}), ...);
}
template <int N_, typename F>
__device__ __forceinline__ void static_for(F&& f) {
    static_for_impl(static_cast<F&&>(f), std::make_integer_sequence<int, N_>{});
}

template <int N_>
__device__ __forceinline__ void wait_vmcnt() {
    static_assert(N_ <= 63, "vmcnt range");
    __builtin_amdgcn_s_waitcnt((N_ & 0xF) | (0x7 << 4) | (0xF << 8) | ((N_ >> 4) << 14));
}

__device__ __forceinline__ void memfence_sched() { __builtin_amdgcn_sched_barrier(0x000F); }

__device__ __forceinline__ float elu_f(float v) { return v > 0.f ? v : expm1f(v); }

__device__ __forceinline__ unsigned char to_fp8(float v) {
    __hip_fp8_e4m3 q(v);
    return (unsigned char)q.__x;
}

// 8 packed fp8 e4m3 -> bf16x8
__device__ __forceinline__ bf16x8 dq8(long v) {
    bf16x8 r;
#pragma unroll
    for (int j = 0; j < 8; ++j) {
        __hip_fp8_e4m3 q;
        q.__x = (unsigned char)(v >> (8 * j));
        r[j] = (__bf16)(float)q;
    }
    return r;
}

// ------------------------------------------------ weight prep (all bf16 frag-major)
// dst chunk ((k/64)*8 + (k%64)/8)*C + col, elem k%8  <- src[col*K+k]
template <int K, int C>
__device__ __forceinline__ void swz_one(const float* __restrict__ src, __bf16* __restrict__ dst, int j)
{
    int col = j / K;
    int k = j & (K - 1);
    int chunk = ((k >> 6) * 8 + ((k & 63) >> 3)) * C + col;
    dst[chunk * 8 + (k & 7)] = (__bf16)src[j];
}

__global__ __launch_bounds__(256) void cvt_swz_kernel(const float* __restrict__ w1,
                                                      const float* __restrict__ w2,
                                                      const float* __restrict__ w3,
                                                      const float* __restrict__ f1,
                                                      const float* __restrict__ f2,
                                                      __bf16* __restrict__ d1,
                                                      __bf16* __restrict__ d2,
                                                      __bf16* __restrict__ d3,
                                                      __bf16* __restrict__ df1,
                                                      __bf16* __restrict__ df2p)
{
    int i = blockIdx.x * 256 + threadIdx.x;
    if (i < 8192)        swz_one<256, 32>(w1, d1, i);
    else if (i < 40960)  swz_one<512, 64>(w2, d2, i - 8192);
    else if (i < 172032) swz_one<1024, 128>(w3, d3, i - 40960);
    else if (i < 204800) swz_one<128, 256>(f1, df1, i - 172032);
    else if (i < 212992) {
        // fc2 padded to 32 cols, frag-major (K=256, C=32); inverse map over DEST index
        int d = i - 204800;
        int e = d & 7;
        int chunkIdx = d >> 3;
        int col = chunkIdx & 31;
        int q = chunkIdx >> 5;
        int k = (q >> 3) * 64 + (q & 7) * 8 + e;
        df2p[d] = (col < 12) ? (__bf16)f2[col * 256 + k] : (__bf16)0.f;
    }
}

// ------------------------------------------------ idx transpose: idxT[s*N + n] = idx[n*16 + s]
__global__ __launch_bounds__(256) void idxT_kernel(const int* __restrict__ idx,
                                                   int* __restrict__ idxT, int N)
{
    int i = blockIdx.x * 256 + threadIdx.x;
    if (i >= N * 16) return;
    int n = i >> 4, s = i & 15;
    idxT[s * N + n] = idx[i];
}

// ---------------------------------------------------------------- fc0: [N,3] -> [N,16] bf16
__global__ __launch_bounds__(256) void fc0_kernel(const float* __restrict__ x,
                                                  const float* __restrict__ w,
                                                  const float* __restrict__ b,
                                                  __bf16* __restrict__ h0, int N)
{
    int n = blockIdx.x * 256 + threadIdx.x;
    if (n >= N) return;
    float x0 = x[n * 3 + 0], x1 = x[n * 3 + 1], x2 = x[n * 3 + 2];
    __bf16 ob[16];
#pragma unroll
    for (int j = 0; j < 16; ++j)
        ob[j] = (__bf16)elu_f(w[j * 3 + 0] * x0 + w[j * 3 + 1] * x1 + w[j * 3 + 2] * x2 + b[j]);
    int4* dst = (int4*)&h0[(size_t)n * 16];
    dst[0] = *(int4*)&ob[0];
    dst[1] = *(int4*)&ob[8];
}

// ------------------------------------------- depth-1 pipelined bf16 MFMA gather-GEMM (R12)
// OUTF8: epilogue emits fp8 e4m3 instead of bf16 (used by spiral2 -> h2).
template <int CIN, int S, int COUT_B, int COUT_TOT, int TILE_M, int RW, int CW,
          bool GATHER, bool OUTF8, int MINW, int NN>
__global__ __launch_bounds__(256, MINW) void mfma_layer(const __bf16* __restrict__ hin,
                                                        const int* __restrict__ idxT,
                                                        const __bf16* __restrict__ Wsw,
                                                        const float* __restrict__ bias,
                                                        void* __restrict__ hout)
{
    constexpr int K = CIN * S;
    constexpr int NSTEP = K / 64;
    static_assert(K % 64 == 0, "K%64");
    constexpr int WM = TILE_M / RW;
    constexpr int WN = COUT_B / CW;
    constexpr int MT = WM / 32;
    constexpr int NT = WN / 32;
    constexpr int IPS = GATHER ? (64 / CIN) : 1;
    constexpr int D = WM / 8;
    constexpr int Bn = NT * 4;
    constexpr int I = GATHER ? D : 0;
    constexpr int NBUFS = 2;
    static_assert(RW * CW == 4, "4 waves");
    static_assert(WM == 32 || WM == 64, "1-2 row subtiles per wave");

    constexpr int AB = 4 * NBUFS * WM * 128;
    constexpr int CB = OUTF8 ? TILE_M * (COUT_B + 16) : TILE_M * (COUT_B + 8) * 2;
    constexpr int SH = AB > CB ? AB : CB;
    __shared__ __align__(16) char smem[SH];

    const int tid = threadIdx.x;
    const int lane = tid & 63;
    const int w = tid >> 6;
    const int wr = w / CW;
    const int wc = w % CW;
    const int ml = lane & 31;
    const int kh = lane >> 5;
    const int m0 = blockIdx.x * TILE_M;
    const int col0 = blockIdx.y * COUT_B;
    const int rbase = m0 + wr * WM;

    char* const Aw = smem + w * (NBUFS * WM * 128);

    int ioff[GATHER ? D : 1];
    int koff[GATHER ? D : 1];
    int gmr[GATHER ? 1 : D];
    int coff[GATHER ? 1 : D];
#pragma unroll
    for (int i = 0; i < D; ++i) {
        int r = i * 8 + (lane >> 3);
        int c = (lane & 7) ^ (r & 7);
        int gm = rbase + r; if (gm >= NN) gm = NN - 1;
        if constexpr (GATHER) {
            ioff[i] = ((c * 8) / CIN) * NN + gm;
            koff[i] = (c * 8) & (CIN - 1);
        } else {
            gmr[i] = gm;
            coff[i] = c * 8;
        }
    }

    bf16x8 bfr[2][NT][4];
    int myIdx[GATHER ? 3 : 1][GATHER ? D : 1];

    const __bf16* wlane = Wsw + ((size_t)(col0 + wc * WN + ml) + (size_t)kh * COUT_TOT) * 8;

    auto loadB = [&](auto sc) {
        constexpr int s = decltype(sc)::value;
        if constexpr (s < NSTEP) {
#pragma unroll
            for (int ni = 0; ni < NT; ++ni)
#pragma unroll
                for (int ks = 0; ks < 4; ++ks)
                    bfr[s & 1][ni][ks] = *(const bf16x8*)(wlane
                        + (size_t)(s * 8 + ks * 2) * COUT_TOT * 8 + ni * 32 * 8);
        }
    };
    auto loadIdxS = [&](auto sc) {
        constexpr int s = decltype(sc)::value;
        if constexpr (GATHER && s < NSTEP) {
#pragma unroll
            for (int i = 0; i < D; ++i)
                myIdx[s % 3][i] = idxT[(s * IPS) * NN + ioff[i]];
        }
    };
    auto issueDMA = [&](auto sc) {
        constexpr int s = decltype(sc)::value;
        if constexpr (s < NSTEP) {
            char* base = Aw + (s % NBUFS) * (WM * 128);
#pragma unroll
            for (int i = 0; i < D; ++i) {
                const __bf16* src;
                if constexpr (GATHER)
                    src = hin + (size_t)myIdx[s % 3][i] * CIN + koff[i];
                else
                    src = hin + (size_t)gmr[i] * K + s * 64 + coff[i];
                __builtin_amdgcn_global_load_lds(
                    (const __attribute__((address_space(1))) void*)src,
                    (__attribute__((address_space(3))) void*)(base + i * 1024),
                    16, 0, 0);
            }
        }
    };

    f32x16 acc[MT][NT];
#pragma unroll
    for (int mi = 0; mi < MT; ++mi)
#pragma unroll
        for (int ni = 0; ni < NT; ++ni) { f32x16 z = {}; acc[mi][ni] = z; }

    loadIdxS(ic<0>{});
    loadIdxS(ic<1>{});
    memfence_sched();
    loadB(ic<0>{});
    memfence_sched();
    issueDMA(ic<0>{});
    memfence_sched();
    loadIdxS(ic<2>{});
    memfence_sched();

    static_for<NSTEP>([&](auto sc) {
        constexpr int s = decltype(sc)::value;
        loadB(ic<s + 1>{});
        memfence_sched();
        issueDMA(ic<s + 1>{});
        memfence_sched();
        loadIdxS(ic<s + 3>{});
        memfence_sched();
        constexpr int NW = I * (s + 2 < NSTEP) + (Bn + D) * (s + 1 < NSTEP)
                         + I * (s + 3 < NSTEP);
        wait_vmcnt<NW>();
        memfence_sched();

        const char* base = Aw + (s % NBUFS) * (WM * 128);
        bf16x8 afr[MT][4];
#pragma unroll
        for (int mi = 0; mi < MT; ++mi)
#pragma unroll
            for (int ks = 0; ks < 4; ++ks) {
                int cb = ks * 2 + kh;
                afr[mi][ks] = *(const bf16x8*)(base + ((mi * 32 + ml) * 8 + (cb ^ (ml & 7))) * 16);
            }
#pragma unroll
        for (int ks = 0; ks < 4; ++ks)
#pragma unroll
            for (int mi = 0; mi < MT; ++mi)
#pragma unroll
                for (int ni = 0; ni < NT; ++ni)
                    acc[mi][ni] = __builtin_amdgcn_mfma_f32_32x32x16_bf16(
                        afr[mi][ks], bfr[s & 1][ni][ks], acc[mi][ni], 0, 0, 0);
    });

    // ---- epilogue
    __syncthreads();
    if constexpr (OUTF8) {
        unsigned char* Cs8 = (unsigned char*)smem;
        constexpr int LDC8 = COUT_B + 16;
#pragma unroll
        for (int ni = 0; ni < NT; ++ni) {
            const int col = wc * WN + ni * 32 + ml;
            const float bv = bias[col0 + col];
#pragma unroll
            for (int mi = 0; mi < MT; ++mi) {
#pragma unroll
                for (int r = 0; r < 16; ++r) {
                    int row = wr * WM + mi * 32 + ((r & 3) + 8 * (r >> 2) + 4 * kh);
                    Cs8[row * LDC8 + col] = to_fp8(elu_f(acc[mi][ni][r] + bv));
                }
            }
        }
        __syncthreads();
        constexpr int C16 = COUT_B / 16;
#pragma unroll
        for (int j2 = tid; j2 < TILE_M * C16; j2 += 256) {
            int row = j2 / C16, c16 = j2 % C16;
            int gm = m0 + row;
            if (gm < NN)
                *(int4*)((unsigned char*)hout + (size_t)gm * COUT_TOT + col0 + c16 * 16)
                    = *(int4*)&Cs8[row * LDC8 + c16 * 16];
        }
    } else {
        __bf16* Cs = (__bf16*)smem;
        constexpr int LDC = COUT_B + 8;
#pragma unroll
        for (int ni = 0; ni < NT; ++ni) {
            const int col = wc * WN + ni * 32 + ml;
            const float bv = bias[col0 + col];
#pragma unroll
            for (int mi = 0; mi < MT; ++mi) {
#pragma unroll
                for (int r = 0; r < 16; ++r) {
                    int row = wr * WM + mi * 32 + ((r & 3) + 8 * (r >> 2) + 4 * kh);
                    Cs[row * LDC + col] = (__bf16)elu_f(acc[mi][ni][r] + bv);
                }
            }
        }
        __syncthreads();
        constexpr int C8 = COUT_B / 8;
#pragma unroll
        for (int j2 = tid; j2 < TILE_M * C8; j2 += 256) {
            int row = j2 / C8, c8 = j2 % C8;
            int gm = m0 + row;
            if (gm < NN)
                *(int4*)&((__bf16*)hout)[(size_t)gm * COUT_TOT + col0 + c8 * 8] = *(int4*)&Cs[row * LDC + c8 * 8];
        }
    }
}

// ------------------------------------------- spiral3 MIXED: fp8 h2 gather + bf16 MFMA
// TILE 64 (RW=2, CW=2), wave 32x64, K=1024, NSTEP=16. A: ds_read_b64 fp8 -> dequant
// to bf16x8 in VGPRs. B: bf16 frag-major w3 (exact).
__global__ __launch_bounds__(256, 3) void mfma3_mixed(const unsigned char* __restrict__ h2f8, // [N,64] e4m3
                                                      const int* __restrict__ idxT,
                                                      const __bf16* __restrict__ Wsw,         // bf16 frag-major (K=1024,C=128)
                                                      const float* __restrict__ bias,
                                                      __bf16* __restrict__ h3)
{
    constexpr int NN = 100000;
    constexpr int NSTEP = 16;
    constexpr int D = 2;        // DMA insts per step per wave (32 rows x 64 B)
    constexpr int Bn = 8;       // B vmem loads per step
    constexpr int I = 2;        // idx loads per step
    __shared__ __align__(16) char smem[17408];   // A: 4x2x2KB=16KB; epilogue 64x136 bf16

    const int tid = threadIdx.x;
    const int lane = tid & 63;
    const int w = tid >> 6;
    const int wr = w >> 1;
    const int wc = w & 1;
    const int ml = lane & 31;
    const int kh = lane >> 5;
    const int m0 = blockIdx.x * 64;
    const int rbase = m0 + wr * 32;

    char* const Aw = smem + w * 4096;

    // DMA geometry: inst i, lane t -> row i*16+(t>>2), phys chunk t&3 holds src chunk (t&3)^(r&3)
    int ioff[D], koff[D];
#pragma unroll
    for (int i = 0; i < D; ++i) {
        int r = i * 16 + (lane >> 2);
        int c = (lane & 3) ^ (r & 3);
        int gm = rbase + r; if (gm >= NN) gm = NN - 1;
        ioff[i] = gm;
        koff[i] = c * 16;
    }

    bf16x8 bfr[2][2][4];
    int myIdx[3][D];

    const __bf16* wlane = Wsw + ((size_t)(wc * 64 + ml) + (size_t)kh * 128) * 8;

    auto loadB = [&](auto sc) {
        constexpr int s = decltype(sc)::value;
        if constexpr (s < NSTEP) {
#pragma unroll
            for (int ni = 0; ni < 2; ++ni)
#pragma unroll
                for (int ks = 0; ks < 4; ++ks)
                    bfr[s & 1][ni][ks] = *(const bf16x8*)(wlane
                        + (size_t)(s * 8 + ks * 2) * 128 * 8 + ni * 32 * 8);
        }
    };
    auto loadIdxS = [&](auto sc) {
        constexpr int s = decltype(sc)::value;
        if constexpr (s < NSTEP) {
#pragma unroll
            for (int i = 0; i < D; ++i)
                myIdx[s % 3][i] = idxT[(size_t)s * NN + ioff[i]];
        }
    };
    auto issueDMA = [&](auto sc) {
        constexpr int s = decltype(sc)::value;
        if constexpr (s < NSTEP) {
            char* base = Aw + (s & 1) * 2048;
#pragma unroll
            for (int i = 0; i < D; ++i) {
                const unsigned char* src = h2f8 + (size_t)myIdx[s % 3][i] * 64 + koff[i];
                __builtin_amdgcn_global_load_lds(
                    (const __attribute__((address_space(1))) void*)src,
                    (__attribute__((address_space(3))) void*)(base + i * 1024),
                    16, 0, 0);
            }
        }
    };

    f32x16 acc[2];
    { f32x16 z = {}; acc[0] = z; acc[1] = z; }

    loadIdxS(ic<0>{});
    loadIdxS(ic<1>{});
    memfence_sched();
    loadB(ic<0>{});
    memfence_sched();
    issueDMA(ic<0>{});
    memfence_sched();
    loadIdxS(ic<2>{});
    memfence_sched();

    static_for<NSTEP>([&](auto sc) {
        constexpr int s = decltype(sc)::value;
        loadB(ic<s + 1>{});
        memfence_sched();
        issueDMA(ic<s + 1>{});
        memfence_sched();
        loadIdxS(ic<s + 3>{});
        memfence_sched();
        constexpr int NW = I * (s + 2 < NSTEP) + (Bn + D) * (s + 1 < NSTEP)
                         + I * (s + 3 < NSTEP);
        wait_vmcnt<NW>();
        memfence_sched();

        const char* base = Aw + (s & 1) * 2048;
        bf16x8 afr[4];
#pragma unroll
        for (int ks = 0; ks < 4; ++ks) {
            long a8 = *(const long*)(base + ml * 64 + ((ks ^ (ml & 3)) << 4) + kh * 8);
            afr[ks] = dq8(a8);   // fp8 e4m3 -> bf16 (exact: bf16 superset of e4m3)
        }
#pragma unroll
        for (int ks = 0; ks < 4; ++ks)
#pragma unroll
            for (int ni = 0; ni < 2; ++ni)
                acc[ni] = __builtin_amdgcn_mfma_f32_32x32x16_bf16(
                    afr[ks], bfr[s & 1][ni][ks], acc[ni], 0, 0, 0);
    });

    // ---- epilogue: bf16 h3, coalesced
    __syncthreads();
    __bf16* Cs = (__bf16*)smem;
#pragma unroll
    for (int ni = 0; ni < 2; ++ni) {
        const int col = wc * 64 + ni * 32 + ml;
        const float bv = bias[col];
#pragma unroll
        for (int r = 0; r < 16; ++r) {
            int row = wr * 32 + ((r & 3) + 8 * (r >> 2) + 4 * kh);
            Cs[row * 136 + col] = (__bf16)elu_f(acc[ni][r] + bv);
        }
    }
    __syncthreads();
#pragma unroll
    for (int j2 = tid; j2 < 64 * 16; j2 += 256) {
        int row = j2 >> 4, c8 = j2 & 15;
        int gm = m0 + row;
        if (gm < NN)
            *(int4*)&h3[(size_t)gm * 128 + c8 * 8] = *(int4*)&Cs[row * 136 + c8 * 8];
    }
}

// ------------------------------------------- FUSED fc1 + fc2(MFMA) + log_softmax (R15)
__global__ __launch_bounds__(256, 3) void fc12_kernel(const __bf16* __restrict__ h3,   // [N,128]
                                                      const __bf16* __restrict__ Wsw,  // fc1 frag-major (K=128,C=256)
                                                      const float* __restrict__ bias1,
                                                      const __bf16* __restrict__ W2p,  // fc2 frag-major padded (K=256,C=32)
                                                      const float* __restrict__ bias2,
                                                      float* __restrict__ out)
{
    __shared__ __align__(16) char smem[32 * 264 * 2];
    const int tid = threadIdx.x;
    const int lane = tid & 63;
    const int w = tid >> 6;
    const int ml = lane & 31;
    const int kh = lane >> 5;
    const int m0 = blockIdx.x * 32;

    const __bf16* wlane = Wsw + ((size_t)(w * 64 + ml) + (size_t)kh * 256) * 8;
    bf16x8 bfr[2][2][4];
#pragma unroll
    for (int s = 0; s < 2; ++s)
#pragma unroll
        for (int ni = 0; ni < 2; ++ni)
#pragma unroll
            for (int ks = 0; ks < 4; ++ks)
                bfr[s][ni][ks] = *(const bf16x8*)(wlane
                    + (size_t)(s * 8 + ks * 2) * 256 * 8 + ni * 32 * 8);

    bf16x8 b2f[4];
#pragma unroll
    for (int ks = 0; ks < 4; ++ks)
        b2f[ks] = *(const bf16x8*)&W2p[((w * 8 + ks * 2 + kh) * 32 + ml) * 8];

#pragma unroll
    for (int t = 0; t < 2; ++t) {
        int j = w * 2 + t;
        int lr = j * 4 + (lane >> 4);
        int sc = (lane & 15) ^ (lr & 15);
        const __bf16* src = h3 + (size_t)(m0 + lr) * 128 + sc * 8;
        __builtin_amdgcn_global_load_lds(
            (const __attribute__((address_space(1))) void*)src,
            (__attribute__((address_space(3))) void*)(smem + j * 1024),
            16, 0, 0);
    }
    wait_vmcnt<0>();
    __syncthreads();

    f32x16 acc[2];
    { f32x16 z = {}; acc[0] = z; acc[1] = z; }
    const char* Ab = smem;
#pragma unroll
    for (int s = 0; s < 2; ++s) {
        bf16x8 afr[4];
#pragma unroll
        for (int ks = 0; ks < 4; ++ks) {
            int c16 = s * 8 + ks * 2 + kh;
            afr[ks] = *(const bf16x8*)(Ab + ml * 256 + ((c16 ^ (ml & 15)) * 16));
        }
#pragma unroll
        for (int ks = 0; ks < 4; ++ks)
#pragma unroll
            for (int ni = 0; ni < 2; ++ni)
                acc[ni] = __builtin_amdgcn_mfma_f32_32x32x16_bf16(afr[ks], bfr[s][ni][ks], acc[ni], 0, 0, 0);
    }
    __syncthreads();

    __bf16* Cs = (__bf16*)smem;
#pragma unroll
    for (int ni = 0; ni < 2; ++ni) {
        int col = w * 64 + ni * 32 + ml;
        float bv = bias1[col];
#pragma unroll
        for (int r = 0; r < 16; ++r) {
            int row = (r & 3) + 8 * (r >> 2) + 4 * kh;
            Cs[row * 264 + col] = (__bf16)elu_f(acc[ni][r] + bv);
        }
    }
    __syncthreads();

    bf16x8 a2[4];
#pragma unroll
    for (int ks = 0; ks < 4; ++ks)
        a2[ks] = *(const bf16x8*)&Cs[ml * 264 + w * 64 + ks * 16 + kh * 8];
    f32x16 acc2;
    { f32x16 z = {}; acc2 = z; }
#pragma unroll
    for (int ks = 0; ks < 4; ++ks)
        acc2 = __builtin_amdgcn_mfma_f32_32x32x16_bf16(a2[ks], b2f[ks], acc2, 0, 0, 0);
    __syncthreads();

    float* P = (float*)(smem + w * 4096);
#pragma unroll
    for (int r = 0; r < 16; ++r)
        P[((r & 3) + 8 * (r >> 2) + 4 * kh) * 32 + ml] = acc2[r];
    __syncthreads();

    float4 s4 = make_float4(0.f, 0.f, 0.f, 0.f);
#pragma unroll
    for (int pw = 0; pw < 4; ++pw) {
        float4 v = *(float4*)(smem + pw * 4096 + tid * 16);
        s4.x += v.x; s4.y += v.y; s4.z += v.z; s4.w += v.w;
    }
    __syncthreads();
    *(float4*)(smem + tid * 16) = s4;
    __syncthreads();

    if (tid < 32) {
        const float* L = (float*)smem + tid * 32;
        float logits[12], mx = -1e30f;
#pragma unroll
        for (int o = 0; o < 12; ++o) {
            logits[o] = L[o] + bias2[o];
            mx = fmaxf(mx, logits[o]);
        }
        float s = 0.f;
#pragma unroll
        for (int o = 0; o < 12; ++o) s += expf(logits[o] - mx);
        float lse = mx + logf(s);
        int n = m0 + tid;
        float4 o0 = make_float4(logits[0] - lse, logits[1] - lse, logits[2] - lse, logits[3] - lse);
        float4 o1 = make_float4(logits[4] - lse, logits[5] - lse, logits[6] - lse, logits[7] - lse);
        float4 o2 = make_float4(logits[8] - lse, logits[9] - lse, logits[10] - lse, logits[11] - lse);
        *(float4*)&out[(size_t)n * 12 + 0] = o0;
        *(float4*)&out[(size_t)n * 12 + 4] = o1;
        *(float4*)&out[(size_t)n * 12 + 8] = o2;
    }
}

extern "C" void kernel_launch(void* const* d_in, const int* in_sizes, int n_in,
                              void* d_out, int out_size, void* d_ws, size_t ws_size,
                              hipStream_t stream)
{
    const int N = 100000;
    const float* x     = (const float*)d_in[0];
    const int*   idx   = (const int*)  d_in[1];
    const float* fc0_w = (const float*)d_in[2];
    const float* fc0_b = (const float*)d_in[3];
    const float* w1    = (const float*)d_in[4];
    const float* b1    = (const float*)d_in[5];
    const float* w2    = (const float*)d_in[6];
    const float* b2    = (const float*)d_in[7];
    const float* w3    = (const float*)d_in[8];
    const float* b3    = (const float*)d_in[9];
    const float* fc1_w = (const float*)d_in[10];
    const float* fc1_b = (const float*)d_in[11];
    const float* fc2_w = (const float*)d_in[12];
    const float* fc2_b = (const float*)d_in[13];
    float* out = (float*)d_out;

    // ---- workspace layout
    char* ws = (char*)d_ws;
    const int n_w1 = 32 * 256, n_w2 = 64 * 512, n_w3 = 128 * 1024, n_fc1 = 256 * 128;
    const int n_fc2p = 32 * 256;
    const int n_wb = n_w1 + n_w2 + n_w3 + n_fc1 + n_fc2p;   // 212992
    __bf16* w1b = (__bf16*)ws;
    __bf16* w2b = w1b + n_w1;
    __bf16* w3b = w2b + n_w2;
    __bf16* f1b = w3b + n_w3;
    __bf16* f2b = f1b + n_fc1;
    size_t off = ((size_t)n_wb * 2 + 4095) & ~(size_t)4095;
    int* idxT = (int*)(ws + off);              off += (size_t)N * 16 * 4;
    __bf16* h0 = (__bf16*)(ws + off);          off += (size_t)N * 16 * 2;
    __bf16* h1 = (__bf16*)(ws + off);          off += (size_t)N * 32 * 2;
    unsigned char* h2f8 = (unsigned char*)(ws + off);  off += (size_t)N * 64;
    __bf16* h3 = (__bf16*)(ws + off);          off += (size_t)N * 128 * 2;

    cvt_swz_kernel<<<(n_wb + 255) / 256, 256, 0, stream>>>(w1, w2, w3, fc1_w, fc2_w,
                                                           w1b, w2b, w3b, f1b, f2b);
    idxT_kernel<<<(N * 16 + 255) / 256, 256, 0, stream>>>(idx, idxT, N);
    fc0_kernel<<<(N + 255) / 256, 256, 0, stream>>>(x, fc0_w, fc0_b, h0, N);

    // spiral1: 16ch x16 -> 32 bf16. TILE 128 (RW=4, CW=1), NSTEP=4.
    mfma_layer<16, 16, 32, 32, 128, 4, 1, true, false, 3, 100000>
        <<<dim3((N + 127) / 128, 1), 256, 0, stream>>>(h0, idxT, w1b, b1, (void*)h1);
    // spiral2: 32ch x16 -> 64, OUTPUT fp8 h2. TILE 128 (RW=4, CW=1), NSTEP=8.
    mfma_layer<32, 16, 64, 64, 128, 4, 1, true, true, 3, 100000>
        <<<dim3((N + 127) / 128, 1), 256, 0, stream>>>(h1, idxT, w2b, b2, (void*)h2f8);
    // spiral3 MIXED: fp8 h2 gather (halved lines) + bf16 w3 MFMA. [NEW]
    mfma3_mixed<<<(N + 63) / 64, 256, 0, stream>>>(h2f8, idxT, w3b, b3, h3);
    // FUSED fc1 + fc2(MFMA) + log_softmax.
    fc12_kernel<<<N / 32, 256, 0, stream>>>(h3, f1b, fc1_b, f2b, fc2_b, out);
}